// Round 12
// baseline (102.067 us; speedup 1.0000x reference)
//
#include <hip/hip_runtime.h>
#include <stdint.h>

#define D 2048
#define R 64
#define M_TOTAL 8192

typedef float f32x4 __attribute__((ext_vector_type(4)));
typedef __bf16 bf16x8 __attribute__((ext_vector_type(8)));
typedef unsigned short u16x8 __attribute__((ext_vector_type(8)));
typedef unsigned short u16x4 __attribute__((ext_vector_type(4)));

__device__ __forceinline__ unsigned short f2bf(float f) {
  unsigned u = __builtin_bit_cast(unsigned, f);
  u += 0x7FFFu + ((u >> 16) & 1u);
  return (unsigned short)(u >> 16);
}

__device__ __forceinline__ u16x8 pack8(float4 a, float4 b) {
  u16x8 o = { f2bf(a.x), f2bf(a.y), f2bf(a.z), f2bf(a.w),
              f2bf(b.x), f2bf(b.y), f2bf(b.z), f2bf(b.w) };
  return o;
}

__device__ __forceinline__ void gload_lds16(const void* g, void* l) {
  __builtin_amdgcn_global_load_lds(
      (const __attribute__((address_space(1))) void*)g,
      (__attribute__((address_space(3))) void*)l, 16, 0, 0);
}

// Inline-asm global->LDS staging (untracked by compiler hazard pass).
// M0 = wave-uniform LDS byte base; HW writes base + lane*16.
__device__ __forceinline__ void gload_lds_asm(const unsigned short* g, int lds_byte) {
  asm volatile("s_mov_b32 m0, %1\n\t"
               "global_load_lds_dwordx4 %0, off"
               :: "v"(g), "s"(lds_byte)
               : "memory");
}

__device__ __forceinline__ int lds_addr(const void* p) {
  return (int)(size_t)(const __attribute__((address_space(3))) void*)p;
}

// ---------------- fused prep (512 threads/block) ---------------- (unchanged)
__global__ __launch_bounds__(512) void prep_kernel(
    const float* __restrict__ x, const float* __restrict__ A,
    const float* __restrict__ B, const float* __restrict__ C,
    const float* __restrict__ w1, const float* __restrict__ b1,
    const float* __restrict__ w2,
    unsigned short* __restrict__ xbf, unsigned short* __restrict__ st,
    unsigned short* __restrict__ w2bf, unsigned short* __restrict__ hbf) {
  __shared__ unsigned short plds[24576];  // 48 KB shared by roles
  const int t = threadIdx.x;
  const int bx = blockIdx.x;

  if (bx < 256) {
    unsigned short* sX = plds;
    unsigned short* sW = plds + 8192;
    const int m0 = bx * 32;
    const int kq = t >> 7, u = t & 127;
    const int row = u >> 2, c = u & 3;
    const int row_w = u >> 1, cw0 = (u & 1) * 2;
    const float* xp = x + (size_t)(m0 + row) * D + kq * 512 + c * 8;
    const float* wp = w1 + (size_t)row_w * D + kq * 512 + cw0 * 8;
    unsigned short* xw = xbf + (size_t)(m0 + row) * D + kq * 512 + c * 8;
    unsigned short* sXw = sX + kq * 2048 + row * 32 + (c ^ ((row >> 1) & 3)) * 8;
    const int rw2 = (row_w >> 1) & 3;
    unsigned short* sWw0 = sW + kq * 4096 + row_w * 32 + (cw0 ^ rw2) * 8;
    unsigned short* sWw1 = sW + kq * 4096 + row_w * 32 + ((cw0 + 1) ^ rw2) * 8;
    const int w = t >> 6, l = t & 63, lm = l & 15, lk = l >> 4;
    const int kqw = w >> 1, rg = w & 1;
    const int rslot = (lk ^ ((lm >> 1) & 3)) * 8;
    const unsigned short* sXr = sX + kqw * 2048 + (rg * 16 + lm) * 32 + rslot;
    const unsigned short* sWr = sW + kqw * 4096 + lm * 32 + rslot;

    f32x4 acc[4] = {};
    float4 qx[2][2], qw[2][4];
#define HLOADX(P, KT) do { qx[P][0] = *(const float4*)(xp + (KT) * 32); \
                           qx[P][1] = *(const float4*)(xp + (KT) * 32 + 4); } while (0)
#define HLOADW(P, KT) do { qw[P][0] = *(const float4*)(wp + (KT) * 32); \
                           qw[P][1] = *(const float4*)(wp + (KT) * 32 + 4); \
                           qw[P][2] = *(const float4*)(wp + (KT) * 32 + 8); \
                           qw[P][3] = *(const float4*)(wp + (KT) * 32 + 12); } while (0)
    HLOADX(0, 0); HLOADW(0, 0); HLOADX(1, 1); HLOADW(1, 1);
#define HSTEP(P, KT) do { \
    u16x8 ox = pack8(qx[P][0], qx[P][1]); \
    *(u16x8*)(sXw + (P) * 1024) = ox; \
    *(u16x8*)(xw + (KT) * 32) = ox; \
    *(u16x8*)(sWw0 + (P) * 2048) = pack8(qw[P][0], qw[P][1]); \
    *(u16x8*)(sWw1 + (P) * 2048) = pack8(qw[P][2], qw[P][3]); \
    if ((KT) + 2 < 16) { HLOADX(P, (KT) + 2); HLOADW(P, (KT) + 2); } \
    __syncthreads(); \
    { bf16x8 a_ = __builtin_bit_cast(bf16x8, *(const u16x8*)(sXr + (P) * 1024)); \
      _Pragma("unroll") \
      for (int j = 0; j < 4; ++j) { \
        bf16x8 b_ = __builtin_bit_cast(bf16x8, *(const u16x8*)(sWr + (P) * 2048 + j * 512)); \
        acc[j] = __builtin_amdgcn_mfma_f32_16x16x32_bf16(a_, b_, acc[j], 0, 0, 0); \
      } } } while (0)
#pragma unroll 1
    for (int it = 0; it < 8; ++it) { HSTEP(0, it * 2); HSTEP(1, it * 2 + 1); }
#undef HSTEP
#undef HLOADX
#undef HLOADW

    __syncthreads();
    float* red = (float*)plds;
    if (kqw > 0) {
#pragma unroll
      for (int j = 0; j < 4; ++j)
        *(f32x4*)(red + (((((kqw - 1) * 2 + rg) * 4) + j) * 64 + l) * 4) = acc[j];
    }
    __syncthreads();
    if (kqw == 0) {
      int m_base = m0 + rg * 16 + lk * 4;
#pragma unroll
      for (int j = 0; j < 4; ++j) {
        f32x4 s = acc[j];
#pragma unroll
        for (int q = 1; q < 4; ++q)
          s += *(const f32x4*)(red + (((((q - 1) * 2 + rg) * 4) + j) * 64 + l) * 4);
        int n = j * 16 + lm;
        float bv = b1[n];
#pragma unroll
        for (int r = 0; r < 4; ++r) {
          float v = s[r] + bv;
          float g = 0.5f * v * (1.0f + erff(v * 0.70710678118654752f));
          hbf[(size_t)(m_base + r) * R + n] = f2bf(g);
        }
      }
    }
  } else if (bx < 768) {
    unsigned short (*lds)[68] = (unsigned short(*)[68])plds;
    const int id = bx - 256;
    const int k0 = (id >> 5) * 128, n0 = (id & 31) * 64;
#pragma unroll
    for (int q = 0; q < 4; ++q) {
      int rowq = q * 32 + (t >> 4);
      int col = (t & 15) * 4;
      size_t off = (size_t)(k0 + rowq) * D + n0 + col;
      float4 a = *(const float4*)(A + off);
      float4 b = *(const float4*)(B + off);
      float4 cc = *(const float4*)(C + off);
      u16x4 o = { f2bf(a.x + b.x + cc.x), f2bf(a.y + b.y + cc.y),
                  f2bf(a.z + b.z + cc.z), f2bf(a.w + b.w + cc.w) };
      *(u16x4*)(&lds[rowq][col]) = o;
    }
    __syncthreads();
    const int n = t >> 3, kc = (t & 7) * 16;
    u16x8 v0, v1;
#pragma unroll
    for (int jj = 0; jj < 8; ++jj) v0[jj] = lds[kc + jj][n];
#pragma unroll
    for (int jj = 0; jj < 8; ++jj) v1[jj] = lds[kc + 8 + jj][n];
    size_t ooff = (size_t)(n0 + n) * D + k0 + kc;
    *(u16x8*)(st + ooff) = v0;
    *(u16x8*)(st + ooff + 8) = v1;
  } else {
    const int NW4 = (D * R) / 4;  // 32768
    for (int i = (bx - 768) * 512 + t; i < NW4; i += 4 * 512) {
      float4 v = ((const float4*)w2)[i];
      u16x4 o = { f2bf(v.x), f2bf(v.y), f2bf(v.z), f2bf(v.w) };
      *(u16x4*)(w2bf + (size_t)i * 4) = o;
    }
  }
}

// ---------------- main: out = (x @ S) * dt + Dp ----------------
// BK=32, 4-slot LDS ring, ONE phase & ONE barrier per K-tile.
// At any instant: slot t = MFMA regs, t+1 = being ds_read, t+2 = receiving
// stage returns, t+3 = stage issue -- fully disjoint, so no read/write LDS
// hazard and no intra-phase barrier. Reads one-phase-ahead into parity reg
// sets (lgkmcnt(12) counted); stage t+3 each phase (4 asm gload_lds);
// vmcnt(4) at phase end drains t+2 before next phase reads it.
__global__ __launch_bounds__(512, 2) void gemm_kernel(
    const unsigned short* __restrict__ xbf, const unsigned short* __restrict__ st,
    const unsigned short* __restrict__ hbf, const unsigned short* __restrict__ w2bf,
    const float* __restrict__ b2, const float* __restrict__ dp,
    float* __restrict__ out) {
  __shared__ unsigned short sA[4 * 8192];  // 4 slots x 256 rows x 32k = 64 KB
  __shared__ unsigned short sB[4 * 8192];  // 64 KB
  const int tid = threadIdx.x;
  const int w = tid >> 6, l = tid & 63, lk = l >> 4, lm = l & 15;
  const int wm = w >> 2, wn = w & 3;
  int bid = blockIdx.x;
  int wg = (bid & 7) * 32 + (bid >> 3);  // bijective XCD swizzle (256 wgs)
  int mb = wg >> 3, nb = wg & 7;
  int m0 = mb * 256, n0 = nb * 256;

  // stage source: row = tid>>2 in [0,128), granule kg = (tid&3) ^ (row&3)
  const int kg = (tid & 3) ^ ((tid >> 2) & 3);
  const unsigned short* gA = xbf + (size_t)(m0 + (tid >> 2)) * D + kg * 8;
  const unsigned short* gB = st + (size_t)(n0 + (tid >> 2)) * D + kg * 8;
  const int sAb = __builtin_amdgcn_readfirstlane(lds_addr(sA) + w * 1024);
  const int sBb = __builtin_amdgcn_readfirstlane(lds_addr(sB) + w * 1024);

  // fragment reads: phys granule = lk ^ (lm&3)
  const int gsw = (lk ^ (lm & 3)) * 8;
  const int arow = (wm * 128 + lm) * 32;
  const int brow = (wn * 64 + lm) * 32;

  const int NT = D / 32;  // 64
  f32x4 acc[8][4] = {};
  bf16x8 aE[8], bE[4], aO[8], bO[4];

#define LD8(buf, off) __builtin_bit_cast(bf16x8, *(const u16x8*)((buf) + (off)))
#define SB0() __builtin_amdgcn_sched_barrier(0)
#define BAR() __builtin_amdgcn_s_barrier()

#define STAGE_T(T) do { if ((T) < NT) { \
    const unsigned short* ga_ = gA + (T) * 32; \
    int la_ = sAb + ((T) & 3) * 16384; \
    gload_lds_asm(ga_, la_); \
    gload_lds_asm(ga_ + 128 * D, la_ + 8192); \
    const unsigned short* gb_ = gB + (T) * 32; \
    int lb_ = sBb + ((T) & 3) * 16384; \
    gload_lds_asm(gb_, lb_); \
    gload_lds_asm(gb_ + 128 * D, lb_ + 8192); } } while (0)

#define RD_T(S, AR, BR) do { \
    const unsigned short* bA_ = sA + (S) * 8192; \
    const unsigned short* bB_ = sB + (S) * 8192; \
    _Pragma("unroll") for (int i = 0; i < 8; ++i) \
      AR[i] = LD8(bA_, arow + i * 512 + gsw); \
    _Pragma("unroll") for (int j = 0; j < 4; ++j) \
      BR[j] = LD8(bB_, brow + j * 512 + gsw); } while (0)

#define MM32(AR, BR) do { \
    __builtin_amdgcn_s_setprio(1); \
    _Pragma("unroll") for (int i = 0; i < 8; ++i) \
    _Pragma("unroll") for (int j = 0; j < 4; ++j) \
      acc[i][j] = __builtin_amdgcn_mfma_f32_16x16x32_bf16(AR[i], BR[j], acc[i][j], 0, 0, 0); \
    __builtin_amdgcn_s_setprio(0); } while (0)

// One phase = one K-tile. Reads t+1 (slot (KT+1)&3; stale-read harmless at
// KT+1==NT); stage t+3; counted lgkm; 32 MFMA on tile KT's regs; counted
// vmcnt draining t+2; single barrier.
#define PHASE(KT, CA, CB, NA, NB) do { \
    RD_T(((KT) + 1) & 3, NA, NB); \
    STAGE_T((KT) + 3); \
    SB0(); \
    asm volatile("s_waitcnt lgkmcnt(12)" ::: "memory"); \
    SB0(); \
    MM32(CA, CB); \
    SB0(); \
    if ((KT) < NT - 3) asm volatile("s_waitcnt vmcnt(4)" ::: "memory"); \
    else               asm volatile("s_waitcnt vmcnt(0)" ::: "memory"); \
    SB0(); BAR(); } while (0)

  // prologue: stage tiles 0,1,2 (12 loads); drain t0,t1 (leave t2); read t0
  STAGE_T(0); STAGE_T(1); STAGE_T(2);
  asm volatile("s_waitcnt vmcnt(4)" ::: "memory");
  BAR();
  RD_T(0, aE, bE);
  SB0();

#pragma unroll 1
  for (int it = 0; it < NT / 2; ++it) {
    const int kt0 = it * 2;
    PHASE(kt0, aE, bE, aO, bO);
    PHASE(kt0 + 1, aO, bO, aE, bE);
  }

  // epilogue: dt = h @ W2^T + b2 (rank-64), out = acc*dt + Dp
  bf16x8 wb0[4], wb1[4];
  float b2v[4], dpv[4];
#pragma unroll
  for (int j = 0; j < 4; ++j) {
    int n = n0 + wn * 64 + j * 16 + lm;
    const u16x8* wp = (const u16x8*)(w2bf + (size_t)n * R + lk * 8);
    wb0[j] = __builtin_bit_cast(bf16x8, wp[0]);
    wb1[j] = __builtin_bit_cast(bf16x8, wp[4]);  // +32 bf16
    b2v[j] = b2[n];
    dpv[j] = dp[n];
  }
#pragma unroll
  for (int mi = 0; mi < 8; ++mi) {
    int hrow = m0 + wm * 128 + mi * 16 + lm;
    const u16x8* hp = (const u16x8*)(hbf + (size_t)hrow * R + lk * 8);
    bf16x8 ha0 = __builtin_bit_cast(bf16x8, hp[0]);
    bf16x8 ha1 = __builtin_bit_cast(bf16x8, hp[4]);
    int mbase = m0 + wm * 128 + mi * 16 + lk * 4;
#pragma unroll
    for (int j = 0; j < 4; ++j) {
      f32x4 dt = {};
      dt = __builtin_amdgcn_mfma_f32_16x16x32_bf16(ha0, wb0[j], dt, 0, 0, 0);
      dt = __builtin_amdgcn_mfma_f32_16x16x32_bf16(ha1, wb1[j], dt, 0, 0, 0);
      int n = n0 + wn * 64 + j * 16 + lm;
#pragma unroll
      for (int r = 0; r < 4; ++r) {
        float val = acc[mi][j][r] * (dt[r] + b2v[j]) + dpv[j];
        out[(size_t)(mbase + r) * D + n] = val;
      }
    }
  }
#undef PHASE
#undef MM32
#undef RD_T
#undef STAGE_T
#undef BAR
#undef SB0
#undef LD8
}

extern "C" void kernel_launch(void* const* d_in, const int* in_sizes, int n_in,
                              void* d_out, int out_size, void* d_ws, size_t ws_size,
                              hipStream_t stream) {
  const float* x  = (const float*)d_in[0];
  const float* A  = (const float*)d_in[1];
  const float* B  = (const float*)d_in[2];
  const float* C  = (const float*)d_in[3];
  const float* Dp = (const float*)d_in[4];
  const float* W1 = (const float*)d_in[5];
  const float* b1 = (const float*)d_in[6];
  const float* W2 = (const float*)d_in[7];
  const float* b2 = (const float*)d_in[8];
  float* out = (float*)d_out;

  uint8_t* ws = (uint8_t*)d_ws;
  unsigned short* xbf  = (unsigned short*)ws;                                // 32 MB
  unsigned short* st   = (unsigned short*)(ws + (32u << 20));                // 8 MB
  unsigned short* w2bf = (unsigned short*)(ws + (40u << 20));                // 256 KB
  unsigned short* hbf  = (unsigned short*)(ws + (41u << 20));                // 1 MB

  prep_kernel<<<772, 512, 0, stream>>>(x, A, B, C, W1, b1, W2, xbf, st, w2bf, hbf);
  gemm_kernel<<<256, 512, 0, stream>>>(xbf, st, hbf, w2bf, b2, Dp, out);
}